// Round 4
// baseline (11112.075 us; speedup 1.0000x reference)
//
#include <hip/hip_runtime.h>
#include <hip/hip_bf16.h>

#define B_ 1024
#define T_ 128
#define E_ 128
#define U_ 512
#define V_ 32000
#define NC 16   // col chunks (blocks per group)
#define NG 16   // row groups
#define MB 64   // rows per group
#define NB 32   // cols per chunk

#define CTR_OFF 0
#define H0H_OFF (1u << 20)
#define H0L_OFF (3u << 20)
#define H1H_OFF (5u << 20)
#define H1L_OFF (7u << 20)
#define EMBW_OFF (9u << 20)
#define ZERO_BYTES (9u << 20)

typedef unsigned int uint32;
typedef __bf16 bf16x8 __attribute__((ext_vector_type(8)));
typedef float f32x4 __attribute__((ext_vector_type(4)));
typedef unsigned short us8 __attribute__((ext_vector_type(8)));
typedef uint32 u32x4 __attribute__((ext_vector_type(4)));

__device__ __forceinline__ unsigned short f2b(float f) {
  uint32 u = __builtin_bit_cast(uint32, f);
  u += 0x7fffu + ((u >> 16) & 1u);   // RNE
  return (unsigned short)(u >> 16);
}
__device__ __forceinline__ float b2f(unsigned short h) {
  return __builtin_bit_cast(float, (uint32)h << 16);
}

// Swizzled LDS fragment read: row-major [row][K] bf16, byte ^= (row&7)<<4
__device__ __forceinline__ bf16x8 lds_frag(const unsigned short* s, int row, int k, int K) {
  uint32 off = (uint32)((row * K + k) * 2) ^ (uint32)((row & 7) << 4);
  us8 v = *(const us8*)((const char*)s + off);
  return __builtin_bit_cast(bf16x8, v);
}

// Device-coherent (agent-scope, sc1) fragment load: 4 relaxed dword atomics.
// Completes at the Infinity Cache (agent coherence point) -> no buffer_inv needed.
__device__ __forceinline__ bf16x8 g_frag_coh(const unsigned short* p) {
  const uint32* q = (const uint32*)p;
  u32x4 v;
  v[0] = __hip_atomic_load(&q[0], __ATOMIC_RELAXED, __HIP_MEMORY_SCOPE_AGENT);
  v[1] = __hip_atomic_load(&q[1], __ATOMIC_RELAXED, __HIP_MEMORY_SCOPE_AGENT);
  v[2] = __hip_atomic_load(&q[2], __ATOMIC_RELAXED, __HIP_MEMORY_SCOPE_AGENT);
  v[3] = __hip_atomic_load(&q[3], __ATOMIC_RELAXED, __HIP_MEMORY_SCOPE_AGENT);
  return __builtin_bit_cast(bf16x8, v);
}
// Device-coherent h store (sc1-flagged, completes at IF on vmcnt retire).
__device__ __forceinline__ void st_coh(unsigned short* p, unsigned short v) {
  __hip_atomic_store(p, v, __ATOMIC_RELAXED, __HIP_MEMORY_SCOPE_AGENT);
}

// Group barrier with ZERO cache-maintenance ops: h traffic is sc1-coherent at
// IF, so completion (vmcnt drain) + relaxed counter is sufficient.
__device__ __forceinline__ void groupbar(uint32* ctr, int phase, int g, int tid) {
  asm volatile("s_waitcnt vmcnt(0)" ::: "memory");  // own stores at IF
  __syncthreads();                                  // all waves drained
  if (tid == 0) {
    uint32* a = &ctr[(uint32)((phase << 4) | g) << 4];
    __hip_atomic_fetch_add(a, 1u, __ATOMIC_RELAXED, __HIP_MEMORY_SCOPE_AGENT);
    while (__hip_atomic_load(a, __ATOMIC_RELAXED, __HIP_MEMORY_SCOPE_AGENT) < NC)
      __builtin_amdgcn_s_sleep(2);
  }
  __syncthreads();
}

__global__ void rnn_init(unsigned char* ws) {
  const uint4 z = {0u, 0u, 0u, 0u};
  uint4* p = (uint4*)ws;
  size_t n = ZERO_BYTES / 16;
  for (size_t j = (size_t)blockIdx.x * blockDim.x + threadIdx.x; j < n;
       j += (size_t)gridDim.x * blockDim.x)
    p[j] = z;
}

// embW[v][u] = sum_e emb[v][e] * Wx0[e][u], stored bf16. grid (V/64, U/64), 256 thr.
__global__ __launch_bounds__(256) void embw_gemm(const float* __restrict__ emb,
                                                 const float* __restrict__ Wx0,
                                                 unsigned short* __restrict__ embW) {
  const int tid = threadIdx.x;
  const int lane = tid & 63;
  const int wv = tid >> 6;  // 4 waves = 4 row sub-tiles
  const int arow = lane & 15;
  const int kgrp = (lane >> 4) * 8;
  const int vrow = blockIdx.x * 64 + wv * 16;

  bf16x8 a[4];
  for (int kt = 0; kt < 4; ++kt) {
    const float* p = emb + (size_t)(vrow + arow) * E_ + kt * 32 + kgrp;
    float4 f0 = ((const float4*)p)[0];
    float4 f1 = ((const float4*)p)[1];
    us8 u;
    u[0] = f2b(f0.x); u[1] = f2b(f0.y); u[2] = f2b(f0.z); u[3] = f2b(f0.w);
    u[4] = f2b(f1.x); u[5] = f2b(f1.y); u[6] = f2b(f1.z); u[7] = f2b(f1.w);
    a[kt] = __builtin_bit_cast(bf16x8, u);
  }
  const int c0 = blockIdx.y * 64;
  for (int nt = 0; nt < 4; ++nt) {
    const int col = c0 + nt * 16 + (lane & 15);
    f32x4 acc = {0.f, 0.f, 0.f, 0.f};
    for (int kt = 0; kt < 4; ++kt) {
      us8 ub;
      for (int j = 0; j < 8; ++j)
        ub[j] = f2b(Wx0[(size_t)(kt * 32 + kgrp + j) * U_ + col]);
      acc = __builtin_amdgcn_mfma_f32_16x16x32_bf16(a[kt], __builtin_bit_cast(bf16x8, ub),
                                                    acc, 0, 0, 0);
    }
    const int crow = vrow + (lane >> 4) * 4;
    for (int i = 0; i < 4; ++i)
      embW[(size_t)(crow + i) * U_ + col] = f2b(acc[i]);
  }
}

__global__ __launch_bounds__(512) void rnn_main(
    const int* __restrict__ tokens, const float* __restrict__ b0,
    const float* __restrict__ Wh0, const float* __restrict__ Wx1,
    const float* __restrict__ Wh1, const float* __restrict__ b1,
    unsigned char* ws) {
  __shared__ unsigned short sWh0h[NB * U_];   // 32 KB
  __shared__ unsigned short sWh0l[NB * U_];   // 32 KB
  __shared__ unsigned short sWx1h[NB * U_];   // 32 KB
  __shared__ unsigned short sWh1h[NB * U_];   // 32 KB
  __shared__ unsigned short sWh1l[NB * 480];  // 30 KB (K-tiles 0..14)
  __shared__ int sTok[MB];

  const int tid = threadIdx.x;
  const int bid = blockIdx.x;
  const int g = bid & (NG - 1);  // row group
  const int c = bid >> 4;        // col chunk
  const int r0 = g * MB;
  const int c0 = c * NB;

  uint32* ctr = (uint32*)(ws + CTR_OFF);
  unsigned short* h0h = (unsigned short*)(ws + H0H_OFF);
  unsigned short* h0l = (unsigned short*)(ws + H0L_OFF);
  unsigned short* h1h = (unsigned short*)(ws + H1H_OFF);
  unsigned short* h1l = (unsigned short*)(ws + H1L_OFF);
  const unsigned short* embW = (const unsigned short*)(ws + EMBW_OFF);

  // ---- stage weight slices: f32 global -> bf16 hi(+lo) swizzled LDS ----
  for (int idx = tid; idx < NB * U_; idx += 512) {
    int cl = idx & 31, k = idx >> 5;
    float v = Wh0[(size_t)k * U_ + c0 + cl];
    unsigned short hi = f2b(v);
    uint32 off = (uint32)((cl * U_ + k) * 2) ^ (uint32)((cl & 7) << 4);
    *(unsigned short*)((char*)sWh0h + off) = hi;
    *(unsigned short*)((char*)sWh0l + off) = f2b(v - b2f(hi));
  }
  for (int idx = tid; idx < NB * U_; idx += 512) {
    int cl = idx & 31, k = idx >> 5;
    float v = Wx1[(size_t)k * U_ + c0 + cl];
    uint32 off = (uint32)((cl * U_ + k) * 2) ^ (uint32)((cl & 7) << 4);
    *(unsigned short*)((char*)sWx1h + off) = f2b(v);
  }
  for (int idx = tid; idx < NB * U_; idx += 512) {
    int cl = idx & 31, k = idx >> 5;
    float v = Wh1[(size_t)k * U_ + c0 + cl];
    unsigned short hi = f2b(v);
    uint32 off = (uint32)((cl * U_ + k) * 2) ^ (uint32)((cl & 7) << 4);
    *(unsigned short*)((char*)sWh1h + off) = hi;
    if (k < 480) {
      uint32 offl = (uint32)((cl * 480 + k) * 2) ^ (uint32)((cl & 7) << 4);
      *(unsigned short*)((char*)sWh1l + offl) = f2b(v - b2f(hi));
    }
  }

  const int lane = tid & 63;
  const int wv = tid >> 6;        // 8 waves
  const int mt = wv >> 1;         // 0..3  M tile
  const int nt = wv & 1;          // 0..1  N tile
  const int colL = nt * 16 + (lane & 15);
  const int rowB = mt * 16 + ((lane >> 4) << 2);
  const int arow = lane & 15;
  const int kgrp = (lane >> 4) * 8;
  const int rowA = r0 + mt * 16 + arow;
  const float b0v = b0[c0 + colL];
  const float b1v = b1[c0 + colL];

  __syncthreads();

  for (int t = 0; t < T_; ++t) {
    if (tid < MB) sTok[tid] = tokens[(size_t)(r0 + tid) * T_ + t];
    __syncthreads();

    const size_t rbuf = (size_t)((t & 1) ^ 1) * (B_ * U_);
    const size_t wbuf = (size_t)(t & 1) * (B_ * U_);

    // ---- layer 0: h0' = tanh(embW[tok] + h0@Wh0 + b0) ----
    {
      f32x4 acc;
      for (int i = 0; i < 4; ++i)
        acc[i] = b0v + b2f(embW[(size_t)sTok[rowB + i] * U_ + c0 + colL]);
      const unsigned short* aph = h0h + rbuf + (size_t)rowA * U_ + kgrp;
      const unsigned short* apl = h0l + rbuf + (size_t)rowA * U_ + kgrp;
      for (int kt = 0; kt < 16; ++kt) {
        bf16x8 ah = g_frag_coh(aph + kt * 32);
        bf16x8 al = g_frag_coh(apl + kt * 32);
        bf16x8 bh = lds_frag(sWh0h, colL, kt * 32 + kgrp, U_);
        bf16x8 bl = lds_frag(sWh0l, colL, kt * 32 + kgrp, U_);
        acc = __builtin_amdgcn_mfma_f32_16x16x32_bf16(ah, bh, acc, 0, 0, 0);
        acc = __builtin_amdgcn_mfma_f32_16x16x32_bf16(al, bh, acc, 0, 0, 0);
        acc = __builtin_amdgcn_mfma_f32_16x16x32_bf16(ah, bl, acc, 0, 0, 0);
      }
      size_t ob = wbuf + (size_t)(r0 + rowB) * U_ + (c0 + colL);
      for (int i = 0; i < 4; ++i) {
        float v = tanhf(acc[i]);
        unsigned short hi = f2b(v);
        st_coh(&h0h[ob + (size_t)i * U_], hi);
        st_coh(&h0l[ob + (size_t)i * U_], f2b(v - b2f(hi)));
      }
    }
    groupbar(ctr, 2 * t, g, tid);

    // ---- layer 1: h1' = tanh(h0'@Wx1 + h1@Wh1 + b1) ----
    {
      f32x4 acc = {b1v, b1v, b1v, b1v};
      const unsigned short* a0h = h0h + wbuf + (size_t)rowA * U_ + kgrp;
      const unsigned short* a0l = h0l + wbuf + (size_t)rowA * U_ + kgrp;
      for (int kt = 0; kt < 16; ++kt) {
        bf16x8 ah = g_frag_coh(a0h + kt * 32);
        bf16x8 al = g_frag_coh(a0l + kt * 32);
        bf16x8 bh = lds_frag(sWx1h, colL, kt * 32 + kgrp, U_);
        acc = __builtin_amdgcn_mfma_f32_16x16x32_bf16(ah, bh, acc, 0, 0, 0);
        acc = __builtin_amdgcn_mfma_f32_16x16x32_bf16(al, bh, acc, 0, 0, 0);
      }
      const unsigned short* a1h = h1h + rbuf + (size_t)rowA * U_ + kgrp;
      const unsigned short* a1l = h1l + rbuf + (size_t)rowA * U_ + kgrp;
      for (int kt = 0; kt < 15; ++kt) {
        bf16x8 ah = g_frag_coh(a1h + kt * 32);
        bf16x8 al = g_frag_coh(a1l + kt * 32);
        bf16x8 bh = lds_frag(sWh1h, colL, kt * 32 + kgrp, U_);
        bf16x8 bl = lds_frag(sWh1l, colL, kt * 32 + kgrp, 480);
        acc = __builtin_amdgcn_mfma_f32_16x16x32_bf16(ah, bh, acc, 0, 0, 0);
        acc = __builtin_amdgcn_mfma_f32_16x16x32_bf16(al, bh, acc, 0, 0, 0);
        acc = __builtin_amdgcn_mfma_f32_16x16x32_bf16(ah, bl, acc, 0, 0, 0);
      }
      {
        bf16x8 ah = g_frag_coh(a1h + 15 * 32);
        bf16x8 al = g_frag_coh(a1l + 15 * 32);
        bf16x8 bh = lds_frag(sWh1h, colL, 15 * 32 + kgrp, U_);
        acc = __builtin_amdgcn_mfma_f32_16x16x32_bf16(ah, bh, acc, 0, 0, 0);
        acc = __builtin_amdgcn_mfma_f32_16x16x32_bf16(al, bh, acc, 0, 0, 0);
      }
      size_t ob = wbuf + (size_t)(r0 + rowB) * U_ + (c0 + colL);
      for (int i = 0; i < 4; ++i) {
        float v = tanhf(acc[i]);
        unsigned short hi = f2b(v);
        st_coh(&h1h[ob + (size_t)i * U_], hi);
        st_coh(&h1l[ob + (size_t)i * U_], f2b(v - b2f(hi)));
      }
    }
    if (t != T_ - 1) groupbar(ctr, 2 * t + 1, g, tid);
  }
}

__global__ void rnn_final(const unsigned short* __restrict__ h1h,
                          const unsigned short* __restrict__ h1l,
                          const float* __restrict__ Wo,
                          const float* __restrict__ bo, float* __restrict__ out) {
  int lane = threadIdx.x & 63;
  int b = blockIdx.x * 4 + (threadIdx.x >> 6);
  us8 hh = *(const us8*)(h1h + (size_t)b * U_ + lane * 8);
  us8 hl = *(const us8*)(h1l + (size_t)b * U_ + lane * 8);
  const float4* wp = (const float4*)(Wo + lane * 8);
  float4 w0 = wp[0], w1 = wp[1];
  float s = (b2f(hh[0]) + b2f(hl[0])) * w0.x + (b2f(hh[1]) + b2f(hl[1])) * w0.y +
            (b2f(hh[2]) + b2f(hl[2])) * w0.z + (b2f(hh[3]) + b2f(hl[3])) * w0.w +
            (b2f(hh[4]) + b2f(hl[4])) * w1.x + (b2f(hh[5]) + b2f(hl[5])) * w1.y +
            (b2f(hh[6]) + b2f(hl[6])) * w1.z + (b2f(hh[7]) + b2f(hl[7])) * w1.w;
  for (int off = 32; off > 0; off >>= 1) s += __shfl_down(s, off, 64);
  if (lane == 0) out[b] = 1.0f / (1.0f + expf(-(s + bo[0])));
}

extern "C" void kernel_launch(void* const* d_in, const int* in_sizes, int n_in,
                              void* d_out, int out_size, void* d_ws, size_t ws_size,
                              hipStream_t stream) {
  const int* tokens = (const int*)d_in[0];
  const float* emb = (const float*)d_in[1];
  const float* Wx0 = (const float*)d_in[2];
  const float* Wh0 = (const float*)d_in[3];
  const float* b0 = (const float*)d_in[4];
  const float* Wx1 = (const float*)d_in[5];
  const float* Wh1 = (const float*)d_in[6];
  const float* b1 = (const float*)d_in[7];
  const float* Wo = (const float*)d_in[8];
  const float* bo = (const float*)d_in[9];
  unsigned char* ws = (unsigned char*)d_ws;
  float* out = (float*)d_out;

  hipLaunchKernelGGL(rnn_init, dim3(1024), dim3(256), 0, stream, ws);
  hipLaunchKernelGGL(embw_gemm, dim3(V_ / 64, U_ / 64), dim3(256), 0, stream,
                     emb, Wx0, (unsigned short*)(ws + EMBW_OFF));
  hipLaunchKernelGGL(rnn_main, dim3(NC * NG), dim3(512), 0, stream, tokens,
                     b0, Wh0, Wx1, Wh1, b1, ws);
  // final h1 lives in buffer (T_-1)&1 == 1
  hipLaunchKernelGGL(rnn_final, dim3(256), dim3(256), 0, stream,
                     (const unsigned short*)(ws + H1H_OFF) + (size_t)1 * B_ * U_,
                     (const unsigned short*)(ws + H1L_OFF) + (size_t)1 * B_ * U_,
                     Wo, bo, out);
}

// Round 5
// 3147.873 us; speedup vs baseline: 3.5300x; 3.5300x over previous
//
#include <hip/hip_runtime.h>
#include <hip/hip_bf16.h>

#define B_ 1024
#define T_ 128
#define E_ 128
#define U_ 512
#define V_ 32000
#define NC 16   // col chunks (blocks per group)
#define NG 16   // row groups
#define MB 64   // rows per group
#define NB 32   // cols per chunk

#define CTR_OFF 0
#define H0H_OFF (1u << 20)
#define H0L_OFF (3u << 20)
#define H1H_OFF (5u << 20)
#define H1L_OFF (7u << 20)
#define EMBW_OFF (9u << 20)
#define ZERO_BYTES (9u << 20)

typedef unsigned int uint32;
typedef __bf16 bf16x8 __attribute__((ext_vector_type(8)));
typedef float f32x4 __attribute__((ext_vector_type(4)));
typedef unsigned short us8 __attribute__((ext_vector_type(8)));

__device__ __forceinline__ unsigned short f2b(float f) {
  uint32 u = __builtin_bit_cast(uint32, f);
  u += 0x7fffu + ((u >> 16) & 1u);   // RNE
  return (unsigned short)(u >> 16);
}
__device__ __forceinline__ float b2f(unsigned short h) {
  return __builtin_bit_cast(float, (uint32)h << 16);
}

// Swizzled LDS fragment read: row-major [row][K] bf16, byte ^= (row&7)<<4
__device__ __forceinline__ bf16x8 lds_frag(const unsigned short* s, int row, int k, int K) {
  uint32 off = (uint32)((row * K + k) * 2) ^ (uint32)((row & 7) << 4);
  us8 v = *(const us8*)((const char*)s + off);
  return __builtin_bit_cast(bf16x8, v);
}
// Normal cached fragment load (L2-served after the per-barrier acquire inv).
__device__ __forceinline__ bf16x8 g_frag(const unsigned short* p) {
  us8 v = *(const us8*)p;
  return __builtin_bit_cast(bf16x8, v);
}
// Device-coherent h store (sc1 write-through: visible at IF on vmcnt retire,
// never dirties L2 -> release needs NO buffer_wbl2).
__device__ __forceinline__ void st_coh(unsigned short* p, unsigned short v) {
  __hip_atomic_store(p, v, __ATOMIC_RELAXED, __HIP_MEMORY_SCOPE_AGENT);
}

// Group barrier: release = vmcnt drain (sc1 stores ack at coherence point) +
// relaxed add; consume = relaxed polls, then ONE agent-acquire fence
// (buffer_inv) per block. No wbl2 anywhere.
__device__ __forceinline__ void groupbar(uint32* ctr, int phase, int g, int tid) {
  asm volatile("s_waitcnt vmcnt(0)" ::: "memory");
  __syncthreads();
  if (tid == 0) {
    uint32* a = &ctr[(uint32)((phase << 4) | g) << 4];
    __hip_atomic_fetch_add(a, 1u, __ATOMIC_RELAXED, __HIP_MEMORY_SCOPE_AGENT);
    while (__hip_atomic_load(a, __ATOMIC_RELAXED, __HIP_MEMORY_SCOPE_AGENT) < NC)
      __builtin_amdgcn_s_sleep(2);
    __builtin_amdgcn_fence(__ATOMIC_ACQUIRE, "agent");
  }
  __syncthreads();
}

__global__ void rnn_init(unsigned char* ws) {
  const uint4 z = {0u, 0u, 0u, 0u};
  uint4* p = (uint4*)ws;
  size_t n = ZERO_BYTES / 16;
  for (size_t j = (size_t)blockIdx.x * blockDim.x + threadIdx.x; j < n;
       j += (size_t)gridDim.x * blockDim.x)
    p[j] = z;
}

// embW[v][u] = sum_e emb[v][e] * Wx0[e][u], stored bf16. grid (V/64, U/64), 256 thr.
__global__ __launch_bounds__(256) void embw_gemm(const float* __restrict__ emb,
                                                 const float* __restrict__ Wx0,
                                                 unsigned short* __restrict__ embW) {
  const int tid = threadIdx.x;
  const int lane = tid & 63;
  const int wv = tid >> 6;  // 4 waves = 4 row sub-tiles
  const int arow = lane & 15;
  const int kgrp = (lane >> 4) * 8;
  const int vrow = blockIdx.x * 64 + wv * 16;

  bf16x8 a[4];
  for (int kt = 0; kt < 4; ++kt) {
    const float* p = emb + (size_t)(vrow + arow) * E_ + kt * 32 + kgrp;
    float4 f0 = ((const float4*)p)[0];
    float4 f1 = ((const float4*)p)[1];
    us8 u;
    u[0] = f2b(f0.x); u[1] = f2b(f0.y); u[2] = f2b(f0.z); u[3] = f2b(f0.w);
    u[4] = f2b(f1.x); u[5] = f2b(f1.y); u[6] = f2b(f1.z); u[7] = f2b(f1.w);
    a[kt] = __builtin_bit_cast(bf16x8, u);
  }
  const int c0 = blockIdx.y * 64;
  for (int nt = 0; nt < 4; ++nt) {
    const int col = c0 + nt * 16 + (lane & 15);
    f32x4 acc = {0.f, 0.f, 0.f, 0.f};
    for (int kt = 0; kt < 4; ++kt) {
      us8 ub;
      for (int j = 0; j < 8; ++j)
        ub[j] = f2b(Wx0[(size_t)(kt * 32 + kgrp + j) * U_ + col]);
      acc = __builtin_amdgcn_mfma_f32_16x16x32_bf16(a[kt], __builtin_bit_cast(bf16x8, ub),
                                                    acc, 0, 0, 0);
    }
    const int crow = vrow + (lane >> 4) * 4;
    for (int i = 0; i < 4; ++i)
      embW[(size_t)(crow + i) * U_ + col] = f2b(acc[i]);
  }
}

__global__ __launch_bounds__(512) void rnn_main(
    const int* __restrict__ tokens, const float* __restrict__ b0,
    const float* __restrict__ Wh0, const float* __restrict__ Wx1,
    const float* __restrict__ Wh1, const float* __restrict__ b1,
    unsigned char* ws) {
  __shared__ unsigned short sWh0h[NB * U_];   // 32 KB
  __shared__ unsigned short sWh0l[NB * U_];   // 32 KB
  __shared__ unsigned short sWx1h[NB * U_];   // 32 KB
  __shared__ unsigned short sWh1h[NB * U_];   // 32 KB
  __shared__ unsigned short sWh1l[NB * 480];  // 30 KB (K-tiles 0..14)
  __shared__ int sTok[MB];

  const int tid = threadIdx.x;
  const int bid = blockIdx.x;
  const int g = bid & (NG - 1);  // row group (group-mates share bid%8 -> same XCD)
  const int c = bid >> 4;        // col chunk
  const int r0 = g * MB;
  const int c0 = c * NB;

  uint32* ctr = (uint32*)(ws + CTR_OFF);
  unsigned short* h0h = (unsigned short*)(ws + H0H_OFF);
  unsigned short* h0l = (unsigned short*)(ws + H0L_OFF);
  unsigned short* h1h = (unsigned short*)(ws + H1H_OFF);
  unsigned short* h1l = (unsigned short*)(ws + H1L_OFF);
  const unsigned short* embW = (const unsigned short*)(ws + EMBW_OFF);

  // ---- stage weight slices: f32 global -> bf16 hi(+lo) swizzled LDS ----
  for (int idx = tid; idx < NB * U_; idx += 512) {
    int cl = idx & 31, k = idx >> 5;
    float v = Wh0[(size_t)k * U_ + c0 + cl];
    unsigned short hi = f2b(v);
    uint32 off = (uint32)((cl * U_ + k) * 2) ^ (uint32)((cl & 7) << 4);
    *(unsigned short*)((char*)sWh0h + off) = hi;
    *(unsigned short*)((char*)sWh0l + off) = f2b(v - b2f(hi));
  }
  for (int idx = tid; idx < NB * U_; idx += 512) {
    int cl = idx & 31, k = idx >> 5;
    float v = Wx1[(size_t)k * U_ + c0 + cl];
    uint32 off = (uint32)((cl * U_ + k) * 2) ^ (uint32)((cl & 7) << 4);
    *(unsigned short*)((char*)sWx1h + off) = f2b(v);
  }
  for (int idx = tid; idx < NB * U_; idx += 512) {
    int cl = idx & 31, k = idx >> 5;
    float v = Wh1[(size_t)k * U_ + c0 + cl];
    unsigned short hi = f2b(v);
    uint32 off = (uint32)((cl * U_ + k) * 2) ^ (uint32)((cl & 7) << 4);
    *(unsigned short*)((char*)sWh1h + off) = hi;
    if (k < 480) {
      uint32 offl = (uint32)((cl * 480 + k) * 2) ^ (uint32)((cl & 7) << 4);
      *(unsigned short*)((char*)sWh1l + offl) = f2b(v - b2f(hi));
    }
  }

  const int lane = tid & 63;
  const int wv = tid >> 6;        // 8 waves
  const int mt = wv >> 1;         // 0..3  M tile
  const int nt = wv & 1;          // 0..1  N tile
  const int colL = nt * 16 + (lane & 15);
  const int rowB = mt * 16 + ((lane >> 4) << 2);
  const int arow = lane & 15;
  const int kgrp = (lane >> 4) * 8;
  const int rowA = r0 + mt * 16 + arow;
  const float b0v = b0[c0 + colL];
  const float b1v = b1[c0 + colL];

  __syncthreads();

  // Window W(t): compute h1'(t-1) (lagged) and h0'(t); ONE barrier per window.
  for (int t = 0; t <= T_; ++t) {
    if (t < T_) {
      if (tid < MB) sTok[tid] = tokens[(size_t)(r0 + tid) * T_ + t];
      __syncthreads();
    }

    // ---- h1'(t-1) = tanh(h0'(t-1)@Wx1 + h1'(t-2)@Wh1 + b1) ----
    if (t >= 1) {
      const size_t rb0 = (size_t)((t - 1) & 1) * (B_ * U_);  // h0'(t-1)
      const size_t rb1 = (size_t)(t & 1) * (B_ * U_);        // h1'(t-2)
      const size_t wb1 = (size_t)((t - 1) & 1) * (B_ * U_);  // h1'(t-1)
      f32x4 acc = {b1v, b1v, b1v, b1v};
      const unsigned short* a0h = h0h + rb0 + (size_t)rowA * U_ + kgrp;
      const unsigned short* a0l = h0l + rb0 + (size_t)rowA * U_ + kgrp;
      for (int kt = 0; kt < 16; ++kt) {
        bf16x8 ah = g_frag(a0h + kt * 32);
        bf16x8 al = g_frag(a0l + kt * 32);
        bf16x8 bh = lds_frag(sWx1h, colL, kt * 32 + kgrp, U_);
        acc = __builtin_amdgcn_mfma_f32_16x16x32_bf16(ah, bh, acc, 0, 0, 0);
        acc = __builtin_amdgcn_mfma_f32_16x16x32_bf16(al, bh, acc, 0, 0, 0);
      }
      const unsigned short* a1h = h1h + rb1 + (size_t)rowA * U_ + kgrp;
      const unsigned short* a1l = h1l + rb1 + (size_t)rowA * U_ + kgrp;
      for (int kt = 0; kt < 15; ++kt) {
        bf16x8 ah = g_frag(a1h + kt * 32);
        bf16x8 al = g_frag(a1l + kt * 32);
        bf16x8 bh = lds_frag(sWh1h, colL, kt * 32 + kgrp, U_);
        bf16x8 bl = lds_frag(sWh1l, colL, kt * 32 + kgrp, 480);
        acc = __builtin_amdgcn_mfma_f32_16x16x32_bf16(ah, bh, acc, 0, 0, 0);
        acc = __builtin_amdgcn_mfma_f32_16x16x32_bf16(al, bh, acc, 0, 0, 0);
        acc = __builtin_amdgcn_mfma_f32_16x16x32_bf16(ah, bl, acc, 0, 0, 0);
      }
      {
        bf16x8 ah = g_frag(a1h + 15 * 32);
        bf16x8 al = g_frag(a1l + 15 * 32);
        bf16x8 bh = lds_frag(sWh1h, colL, 15 * 32 + kgrp, U_);
        acc = __builtin_amdgcn_mfma_f32_16x16x32_bf16(ah, bh, acc, 0, 0, 0);
        acc = __builtin_amdgcn_mfma_f32_16x16x32_bf16(al, bh, acc, 0, 0, 0);
      }
      size_t ob = wb1 + (size_t)(r0 + rowB) * U_ + (c0 + colL);
      for (int i = 0; i < 4; ++i) {
        float v = tanhf(acc[i]);
        unsigned short hi = f2b(v);
        st_coh(&h1h[ob + (size_t)i * U_], hi);
        st_coh(&h1l[ob + (size_t)i * U_], f2b(v - b2f(hi)));
      }
    }

    // ---- h0'(t) = tanh(embW[tok(t)] + h0'(t-1)@Wh0 + b0) ----
    if (t < T_) {
      const size_t rbuf = (size_t)((t & 1) ^ 1) * (B_ * U_);
      const size_t wbuf = (size_t)(t & 1) * (B_ * U_);
      f32x4 acc;
      for (int i = 0; i < 4; ++i)
        acc[i] = b0v + b2f(embW[(size_t)sTok[rowB + i] * U_ + c0 + colL]);
      const unsigned short* aph = h0h + rbuf + (size_t)rowA * U_ + kgrp;
      const unsigned short* apl = h0l + rbuf + (size_t)rowA * U_ + kgrp;
      for (int kt = 0; kt < 16; ++kt) {
        bf16x8 ah = g_frag(aph + kt * 32);
        bf16x8 al = g_frag(apl + kt * 32);
        bf16x8 bh = lds_frag(sWh0h, colL, kt * 32 + kgrp, U_);
        bf16x8 bl = lds_frag(sWh0l, colL, kt * 32 + kgrp, U_);
        acc = __builtin_amdgcn_mfma_f32_16x16x32_bf16(ah, bh, acc, 0, 0, 0);
        acc = __builtin_amdgcn_mfma_f32_16x16x32_bf16(al, bh, acc, 0, 0, 0);
        acc = __builtin_amdgcn_mfma_f32_16x16x32_bf16(ah, bl, acc, 0, 0, 0);
      }
      size_t ob = wbuf + (size_t)(r0 + rowB) * U_ + (c0 + colL);
      for (int i = 0; i < 4; ++i) {
        float v = tanhf(acc[i]);
        unsigned short hi = f2b(v);
        st_coh(&h0h[ob + (size_t)i * U_], hi);
        st_coh(&h0l[ob + (size_t)i * U_], f2b(v - b2f(hi)));
      }
      groupbar(ctr, t, g, tid);
    }
  }
}

__global__ void rnn_final(const unsigned short* __restrict__ h1h,
                          const unsigned short* __restrict__ h1l,
                          const float* __restrict__ Wo,
                          const float* __restrict__ bo, float* __restrict__ out) {
  int lane = threadIdx.x & 63;
  int b = blockIdx.x * 4 + (threadIdx.x >> 6);
  us8 hh = *(const us8*)(h1h + (size_t)b * U_ + lane * 8);
  us8 hl = *(const us8*)(h1l + (size_t)b * U_ + lane * 8);
  const float4* wp = (const float4*)(Wo + lane * 8);
  float4 w0 = wp[0], w1 = wp[1];
  float s = (b2f(hh[0]) + b2f(hl[0])) * w0.x + (b2f(hh[1]) + b2f(hl[1])) * w0.y +
            (b2f(hh[2]) + b2f(hl[2])) * w0.z + (b2f(hh[3]) + b2f(hl[3])) * w0.w +
            (b2f(hh[4]) + b2f(hl[4])) * w1.x + (b2f(hh[5]) + b2f(hl[5])) * w1.y +
            (b2f(hh[6]) + b2f(hl[6])) * w1.z + (b2f(hh[7]) + b2f(hl[7])) * w1.w;
  for (int off = 32; off > 0; off >>= 1) s += __shfl_down(s, off, 64);
  if (lane == 0) out[b] = 1.0f / (1.0f + expf(-(s + bo[0])));
}

extern "C" void kernel_launch(void* const* d_in, const int* in_sizes, int n_in,
                              void* d_out, int out_size, void* d_ws, size_t ws_size,
                              hipStream_t stream) {
  const int* tokens = (const int*)d_in[0];
  const float* emb = (const float*)d_in[1];
  const float* Wx0 = (const float*)d_in[2];
  const float* Wh0 = (const float*)d_in[3];
  const float* b0 = (const float*)d_in[4];
  const float* Wx1 = (const float*)d_in[5];
  const float* Wh1 = (const float*)d_in[6];
  const float* b1 = (const float*)d_in[7];
  const float* Wo = (const float*)d_in[8];
  const float* bo = (const float*)d_in[9];
  unsigned char* ws = (unsigned char*)d_ws;
  float* out = (float*)d_out;

  hipLaunchKernelGGL(rnn_init, dim3(1024), dim3(256), 0, stream, ws);
  hipLaunchKernelGGL(embw_gemm, dim3(V_ / 64, U_ / 64), dim3(256), 0, stream,
                     emb, Wx0, (unsigned short*)(ws + EMBW_OFF));
  hipLaunchKernelGGL(rnn_main, dim3(NC * NG), dim3(512), 0, stream, tokens,
                     b0, Wh0, Wx1, Wh1, b1, ws);
  // final h1'(127) lives in buffer 127&1 == 1
  hipLaunchKernelGGL(rnn_final, dim3(256), dim3(256), 0, stream,
                     (const unsigned short*)(ws + H1H_OFF) + (size_t)1 * B_ * U_,
                     (const unsigned short*)(ws + H1L_OFF) + (size_t)1 * B_ * U_,
                     Wo, bo, out);
}

// Round 6
// 2393.284 us; speedup vs baseline: 4.6430x; 1.3153x over previous
//
#include <hip/hip_runtime.h>
#include <hip/hip_bf16.h>

#define B_ 1024
#define T_ 128
#define E_ 128
#define U_ 512
#define V_ 32000
#define NC 16   // col chunks (blocks per group)
#define NG 16   // row groups
#define MB 64   // rows per group
#define NB 32   // cols per chunk

#define CTR_OFF 0
#define H0H_OFF (1u << 20)
#define H0L_OFF (3u << 20)
#define H1H_OFF (5u << 20)
#define H1L_OFF (7u << 20)
#define EMBW_OFF (9u << 20)
#define ZERO_BYTES (9u << 20)

typedef unsigned int uint32;
typedef __bf16 bf16x8 __attribute__((ext_vector_type(8)));
typedef float f32x4 __attribute__((ext_vector_type(4)));
typedef unsigned short us8 __attribute__((ext_vector_type(8)));

__device__ __forceinline__ unsigned short f2b(float f) {
  uint32 u = __builtin_bit_cast(uint32, f);
  u += 0x7fffu + ((u >> 16) & 1u);   // RNE
  return (unsigned short)(u >> 16);
}
__device__ __forceinline__ float b2f(unsigned short h) {
  return __builtin_bit_cast(float, (uint32)h << 16);
}

// Swizzled LDS fragment read: row-major [row][K] bf16, byte ^= (row&7)<<4
__device__ __forceinline__ bf16x8 lds_frag(const unsigned short* s, int row, int k, int K) {
  uint32 off = (uint32)((row * K + k) * 2) ^ (uint32)((row & 7) << 4);
  us8 v = *(const us8*)((const char*)s + off);
  return __builtin_bit_cast(bf16x8, v);
}
// Normal cached fragment load (L2-served after the per-barrier acquire inv).
__device__ __forceinline__ bf16x8 g_frag(const unsigned short* p) {
  us8 v = *(const us8*)p;
  return __builtin_bit_cast(bf16x8, v);
}
// Device-coherent h store (sc1 write-through: visible at IF on vmcnt retire,
// never dirties L2 -> release needs NO buffer_wbl2).
__device__ __forceinline__ void st_coh(unsigned short* p, unsigned short v) {
  __hip_atomic_store(p, v, __ATOMIC_RELAXED, __HIP_MEMORY_SCOPE_AGENT);
}

// Group barrier: release = vmcnt drain (sc1 stores ack at coherence point) +
// relaxed add; consume = relaxed polls, then ONE agent-acquire fence
// (buffer_inv) per block. No wbl2 anywhere.
__device__ __forceinline__ void groupbar(uint32* ctr, int phase, int g, int tid) {
  asm volatile("s_waitcnt vmcnt(0)" ::: "memory");
  __syncthreads();
  if (tid == 0) {
    uint32* a = &ctr[(uint32)((phase << 4) | g) << 4];
    __hip_atomic_fetch_add(a, 1u, __ATOMIC_RELAXED, __HIP_MEMORY_SCOPE_AGENT);
    while (__hip_atomic_load(a, __ATOMIC_RELAXED, __HIP_MEMORY_SCOPE_AGENT) < NC)
      __builtin_amdgcn_s_sleep(1);
    __builtin_amdgcn_fence(__ATOMIC_ACQUIRE, "agent");
  }
  __syncthreads();
}

__global__ void rnn_init(unsigned char* ws) {
  const uint4 z = {0u, 0u, 0u, 0u};
  uint4* p = (uint4*)ws;
  size_t n = ZERO_BYTES / 16;
  for (size_t j = (size_t)blockIdx.x * blockDim.x + threadIdx.x; j < n;
       j += (size_t)gridDim.x * blockDim.x)
    p[j] = z;
}

// embW[v][u] = sum_e emb[v][e] * Wx0[e][u], stored bf16. grid (V/64, U/64), 256 thr.
__global__ __launch_bounds__(256) void embw_gemm(const float* __restrict__ emb,
                                                 const float* __restrict__ Wx0,
                                                 unsigned short* __restrict__ embW) {
  const int tid = threadIdx.x;
  const int lane = tid & 63;
  const int wv = tid >> 6;  // 4 waves = 4 row sub-tiles
  const int arow = lane & 15;
  const int kgrp = (lane >> 4) * 8;
  const int vrow = blockIdx.x * 64 + wv * 16;

  bf16x8 a[4];
  for (int kt = 0; kt < 4; ++kt) {
    const float* p = emb + (size_t)(vrow + arow) * E_ + kt * 32 + kgrp;
    float4 f0 = ((const float4*)p)[0];
    float4 f1 = ((const float4*)p)[1];
    us8 u;
    u[0] = f2b(f0.x); u[1] = f2b(f0.y); u[2] = f2b(f0.z); u[3] = f2b(f0.w);
    u[4] = f2b(f1.x); u[5] = f2b(f1.y); u[6] = f2b(f1.z); u[7] = f2b(f1.w);
    a[kt] = __builtin_bit_cast(bf16x8, u);
  }
  const int c0 = blockIdx.y * 64;
  for (int nt = 0; nt < 4; ++nt) {
    const int col = c0 + nt * 16 + (lane & 15);
    f32x4 acc = {0.f, 0.f, 0.f, 0.f};
    for (int kt = 0; kt < 4; ++kt) {
      us8 ub;
      for (int j = 0; j < 8; ++j)
        ub[j] = f2b(Wx0[(size_t)(kt * 32 + kgrp + j) * U_ + col]);
      acc = __builtin_amdgcn_mfma_f32_16x16x32_bf16(a[kt], __builtin_bit_cast(bf16x8, ub),
                                                    acc, 0, 0, 0);
    }
    const int crow = vrow + (lane >> 4) * 4;
    for (int i = 0; i < 4; ++i)
      embW[(size_t)(crow + i) * U_ + col] = f2b(acc[i]);
  }
}

__global__ __launch_bounds__(512, 2) void rnn_main(
    const int* __restrict__ tokens, const float* __restrict__ b0,
    const float* __restrict__ Wh0, const float* __restrict__ Wx1,
    const float* __restrict__ Wh1, const float* __restrict__ b1,
    unsigned char* ws) {
  __shared__ unsigned short sWh0h[NB * U_];   // 32 KB
  __shared__ unsigned short sWh0l[NB * U_];   // 32 KB
  __shared__ unsigned short sWx1h[NB * U_];   // 32 KB
  __shared__ unsigned short sWh1h[NB * U_];   // 32 KB
  __shared__ unsigned short sWh1l[NB * 480];  // 30 KB (K-tiles 0..14)

  const int tid = threadIdx.x;
  const int bid = blockIdx.x;
  const int g = bid & (NG - 1);  // row group (group-mates share bid%8 -> same XCD)
  const int c = bid >> 4;        // col chunk
  const int r0 = g * MB;
  const int c0 = c * NB;

  uint32* ctr = (uint32*)(ws + CTR_OFF);
  unsigned short* h0h = (unsigned short*)(ws + H0H_OFF);
  unsigned short* h0l = (unsigned short*)(ws + H0L_OFF);
  unsigned short* h1h = (unsigned short*)(ws + H1H_OFF);
  unsigned short* h1l = (unsigned short*)(ws + H1L_OFF);
  const unsigned short* embW = (const unsigned short*)(ws + EMBW_OFF);

  // ---- stage weight slices: f32 global -> bf16 hi(+lo) swizzled LDS ----
  for (int idx = tid; idx < NB * U_; idx += 512) {
    int cl = idx & 31, k = idx >> 5;
    float v = Wh0[(size_t)k * U_ + c0 + cl];
    unsigned short hi = f2b(v);
    uint32 off = (uint32)((cl * U_ + k) * 2) ^ (uint32)((cl & 7) << 4);
    *(unsigned short*)((char*)sWh0h + off) = hi;
    *(unsigned short*)((char*)sWh0l + off) = f2b(v - b2f(hi));
  }
  for (int idx = tid; idx < NB * U_; idx += 512) {
    int cl = idx & 31, k = idx >> 5;
    float v = Wx1[(size_t)k * U_ + c0 + cl];
    uint32 off = (uint32)((cl * U_ + k) * 2) ^ (uint32)((cl & 7) << 4);
    *(unsigned short*)((char*)sWx1h + off) = f2b(v);
  }
  for (int idx = tid; idx < NB * U_; idx += 512) {
    int cl = idx & 31, k = idx >> 5;
    float v = Wh1[(size_t)k * U_ + c0 + cl];
    unsigned short hi = f2b(v);
    uint32 off = (uint32)((cl * U_ + k) * 2) ^ (uint32)((cl & 7) << 4);
    *(unsigned short*)((char*)sWh1h + off) = hi;
    if (k < 480) {
      uint32 offl = (uint32)((cl * 480 + k) * 2) ^ (uint32)((cl & 7) << 4);
      *(unsigned short*)((char*)sWh1l + offl) = f2b(v - b2f(hi));
    }
  }

  const int lane = tid & 63;
  const int wv = tid >> 6;        // 8 waves
  const int mt = wv >> 1;         // 0..3  M tile
  const int nt = wv & 1;          // 0..1  N tile
  const int colL = nt * 16 + (lane & 15);
  const int rowB = mt * 16 + ((lane >> 4) << 2);
  const int arow = lane & 15;
  const int kgrp = (lane >> 4) * 8;
  const int rowA = r0 + mt * 16 + arow;
  const float b0v = b0[c0 + colL];
  const float b1v = b1[c0 + colL];

  __syncthreads();

  // Prefetch window-0 tokens + embW acc-init (per-lane, no LDS staging).
  unsigned short embPre[4];
  {
    for (int i = 0; i < 4; ++i) {
      int tk = tokens[(size_t)(r0 + rowB + i) * T_ + 0];
      embPre[i] = embW[(size_t)tk * U_ + c0 + colL];
    }
  }

  // Window W(t): compute h1'(t-1) (lagged) and h0'(t); ONE barrier per window.
  for (int t = 0; t <= T_; ++t) {
    const size_t rb0 = (size_t)((t & 1) ^ 1) * (B_ * U_);  // h0'(t-1)

    // ---- load h0'(t-1) fragments ONCE (reused by layer-1 Wx1 and layer-0 Wh0)
    bf16x8 h0h_r[16], h0l_r[16];
    {
      const unsigned short* aph = h0h + rb0 + (size_t)rowA * U_ + kgrp;
      const unsigned short* apl = h0l + rb0 + (size_t)rowA * U_ + kgrp;
#pragma unroll
      for (int kt = 0; kt < 16; ++kt) {
        h0h_r[kt] = g_frag(aph + kt * 32);
        h0l_r[kt] = g_frag(apl + kt * 32);
      }
    }

    // ---- h1'(t-1) = tanh(h0'(t-1)@Wx1 + h1'(t-2)@Wh1 + b1) ----
    if (t >= 1) {
      const size_t rb1 = (size_t)(t & 1) * (B_ * U_);        // h1'(t-2)
      const size_t wb1 = (size_t)((t - 1) & 1) * (B_ * U_);  // h1'(t-1)
      f32x4 acc = {b1v, b1v, b1v, b1v};
      const unsigned short* a1h = h1h + rb1 + (size_t)rowA * U_ + kgrp;
      const unsigned short* a1l = h1l + rb1 + (size_t)rowA * U_ + kgrp;
#pragma unroll
      for (int kt = 0; kt < 16; ++kt) {
        bf16x8 ah = g_frag(a1h + kt * 32);
        bf16x8 al = g_frag(a1l + kt * 32);
        bf16x8 bxh = lds_frag(sWx1h, colL, kt * 32 + kgrp, U_);
        bf16x8 bh = lds_frag(sWh1h, colL, kt * 32 + kgrp, U_);
        acc = __builtin_amdgcn_mfma_f32_16x16x32_bf16(h0h_r[kt], bxh, acc, 0, 0, 0);
        acc = __builtin_amdgcn_mfma_f32_16x16x32_bf16(h0l_r[kt], bxh, acc, 0, 0, 0);
        acc = __builtin_amdgcn_mfma_f32_16x16x32_bf16(ah, bh, acc, 0, 0, 0);
        acc = __builtin_amdgcn_mfma_f32_16x16x32_bf16(al, bh, acc, 0, 0, 0);
        if (kt < 15) {
          bf16x8 bl = lds_frag(sWh1l, colL, kt * 32 + kgrp, 480);
          acc = __builtin_amdgcn_mfma_f32_16x16x32_bf16(ah, bl, acc, 0, 0, 0);
        }
      }
      size_t ob = wb1 + (size_t)(r0 + rowB) * U_ + (c0 + colL);
      for (int i = 0; i < 4; ++i) {
        float v = tanhf(acc[i]);
        unsigned short hi = f2b(v);
        st_coh(&h1h[ob + (size_t)i * U_], hi);
        st_coh(&h1l[ob + (size_t)i * U_], f2b(v - b2f(hi)));
      }
    }

    // ---- h0'(t) = tanh(embW[tok(t)] + h0'(t-1)@Wh0 + b0) ----
    if (t < T_) {
      const size_t wbuf = (size_t)(t & 1) * (B_ * U_);
      f32x4 acc;
      for (int i = 0; i < 4; ++i) acc[i] = b0v + b2f(embPre[i]);
#pragma unroll
      for (int kt = 0; kt < 16; ++kt) {
        bf16x8 bh = lds_frag(sWh0h, colL, kt * 32 + kgrp, U_);
        bf16x8 bl = lds_frag(sWh0l, colL, kt * 32 + kgrp, U_);
        acc = __builtin_amdgcn_mfma_f32_16x16x32_bf16(h0h_r[kt], bh, acc, 0, 0, 0);
        acc = __builtin_amdgcn_mfma_f32_16x16x32_bf16(h0l_r[kt], bh, acc, 0, 0, 0);
        acc = __builtin_amdgcn_mfma_f32_16x16x32_bf16(h0h_r[kt], bl, acc, 0, 0, 0);
      }
      size_t ob = wbuf + (size_t)(r0 + rowB) * U_ + (c0 + colL);
      for (int i = 0; i < 4; ++i) {
        float v = tanhf(acc[i]);
        unsigned short hi = f2b(v);
        st_coh(&h0h[ob + (size_t)i * U_], hi);
        st_coh(&h0l[ob + (size_t)i * U_], f2b(v - b2f(hi)));
      }

      // ---- prefetch NEXT window's tokens+embW init (L2-warm, pre-inv; values
      // land in regs before the acquire fence via the barrier's vmcnt drain).
      if (t + 1 < T_) {
        for (int i = 0; i < 4; ++i) {
          int tk = tokens[(size_t)(r0 + rowB + i) * T_ + (t + 1)];
          embPre[i] = embW[(size_t)tk * U_ + c0 + colL];
        }
      }
      groupbar(ctr, t, g, tid);
    }
  }
}

__global__ void rnn_final(const unsigned short* __restrict__ h1h,
                          const unsigned short* __restrict__ h1l,
                          const float* __restrict__ Wo,
                          const float* __restrict__ bo, float* __restrict__ out) {
  int lane = threadIdx.x & 63;
  int b = blockIdx.x * 4 + (threadIdx.x >> 6);
  us8 hh = *(const us8*)(h1h + (size_t)b * U_ + lane * 8);
  us8 hl = *(const us8*)(h1l + (size_t)b * U_ + lane * 8);
  const float4* wp = (const float4*)(Wo + lane * 8);
  float4 w0 = wp[0], w1 = wp[1];
  float s = (b2f(hh[0]) + b2f(hl[0])) * w0.x + (b2f(hh[1]) + b2f(hl[1])) * w0.y +
            (b2f(hh[2]) + b2f(hl[2])) * w0.z + (b2f(hh[3]) + b2f(hl[3])) * w0.w +
            (b2f(hh[4]) + b2f(hl[4])) * w1.x + (b2f(hh[5]) + b2f(hl[5])) * w1.y +
            (b2f(hh[6]) + b2f(hl[6])) * w1.z + (b2f(hh[7]) + b2f(hl[7])) * w1.w;
  for (int off = 32; off > 0; off >>= 1) s += __shfl_down(s, off, 64);
  if (lane == 0) out[b] = 1.0f / (1.0f + expf(-(s + bo[0])));
}

extern "C" void kernel_launch(void* const* d_in, const int* in_sizes, int n_in,
                              void* d_out, int out_size, void* d_ws, size_t ws_size,
                              hipStream_t stream) {
  const int* tokens = (const int*)d_in[0];
  const float* emb = (const float*)d_in[1];
  const float* Wx0 = (const float*)d_in[2];
  const float* Wh0 = (const float*)d_in[3];
  const float* b0 = (const float*)d_in[4];
  const float* Wx1 = (const float*)d_in[5];
  const float* Wh1 = (const float*)d_in[6];
  const float* b1 = (const float*)d_in[7];
  const float* Wo = (const float*)d_in[8];
  const float* bo = (const float*)d_in[9];
  unsigned char* ws = (unsigned char*)d_ws;
  float* out = (float*)d_out;

  hipLaunchKernelGGL(rnn_init, dim3(1024), dim3(256), 0, stream, ws);
  hipLaunchKernelGGL(embw_gemm, dim3(V_ / 64, U_ / 64), dim3(256), 0, stream,
                     emb, Wx0, (unsigned short*)(ws + EMBW_OFF));
  hipLaunchKernelGGL(rnn_main, dim3(NC * NG), dim3(512), 0, stream, tokens,
                     b0, Wh0, Wx1, Wh1, b1, ws);
  // final h1'(127) lives in buffer 127&1 == 1
  hipLaunchKernelGGL(rnn_final, dim3(256), dim3(256), 0, stream,
                     (const unsigned short*)(ws + H1H_OFF) + (size_t)1 * B_ * U_,
                     (const unsigned short*)(ws + H1L_OFF) + (size_t)1 * B_ * U_,
                     Wo, bo, out);
}

// Round 7
// 2225.169 us; speedup vs baseline: 4.9938x; 1.0756x over previous
//
#include <hip/hip_runtime.h>
#include <hip/hip_bf16.h>

#define B_ 1024
#define T_ 128
#define E_ 128
#define U_ 512
#define V_ 32000
#define NC 16   // col chunks (blocks per group)
#define NG 16   // row groups
#define MB 64   // rows per group
#define NB 32   // cols per chunk

#define CTR_OFF 0
#define XMASK_OFF (512u << 10)
#define H0H_OFF (1u << 20)
#define H0L_OFF (3u << 20)
#define H1H_OFF (5u << 20)
#define H1L_OFF (7u << 20)
#define EMBW_OFF (9u << 20)
#define ZERO_BYTES (9u << 20)

typedef unsigned int uint32;
typedef __bf16 bf16x8 __attribute__((ext_vector_type(8)));
typedef float f32x4 __attribute__((ext_vector_type(4)));
typedef unsigned short us8 __attribute__((ext_vector_type(8)));

__device__ __forceinline__ unsigned short f2b(float f) {
  uint32 u = __builtin_bit_cast(uint32, f);
  u += 0x7fffu + ((u >> 16) & 1u);   // RNE
  return (unsigned short)(u >> 16);
}
__device__ __forceinline__ float b2f(unsigned short h) {
  return __builtin_bit_cast(float, (uint32)h << 16);
}

// Swizzled LDS fragment read: row-major [row][K] bf16, byte ^= (row&7)<<4
__device__ __forceinline__ bf16x8 lds_frag(const unsigned short* s, int row, int k, int K) {
  uint32 off = (uint32)((row * K + k) * 2) ^ (uint32)((row & 7) << 4);
  us8 v = *(const us8*)((const char*)s + off);
  return __builtin_bit_cast(bf16x8, v);
}
// Normal cached fragment load.
__device__ __forceinline__ bf16x8 g_frag(const unsigned short* p) {
  us8 v = *(const us8*)p;
  return __builtin_bit_cast(bf16x8, v);
}
// Device-coherent h store (sc1 write-through, for the cross-XCD fallback path).
__device__ __forceinline__ void st_coh(unsigned short* p, unsigned short v) {
  __hip_atomic_store(p, v, __ATOMIC_RELAXED, __HIP_MEMORY_SCOPE_AGENT);
}
// Store flavor: FAST (same-XCD L2 exchange) = plain cached store.
template <bool FAST>
__device__ __forceinline__ void st_h(unsigned short* p, unsigned short v) {
  if (FAST) *p = v; else st_coh(p, v);
}

// Group barrier core. Release: vmcnt drain (stores committed to L2/IF) +
// relaxed agent add. Consume: relaxed polls, then either a full agent acquire
// fence (fallback, cross-XCD: buffer_inv L2) or an L1-only invalidate (fast,
// same-XCD: peers' stores are already in our shared L2).
__device__ __forceinline__ void bar_core(uint32* ctr, int phase, int g, int tid,
                                         bool fence, bool l1inv) {
  asm volatile("s_waitcnt vmcnt(0)" ::: "memory");
  __syncthreads();
  if (tid == 0) {
    uint32* a = &ctr[(uint32)((phase << 4) | g) << 4];
    __hip_atomic_fetch_add(a, 1u, __ATOMIC_RELAXED, __HIP_MEMORY_SCOPE_AGENT);
    while (__hip_atomic_load(a, __ATOMIC_RELAXED, __HIP_MEMORY_SCOPE_AGENT) < NC)
      __builtin_amdgcn_s_sleep(1);
    if (fence) __builtin_amdgcn_fence(__ATOMIC_ACQUIRE, "agent");
    if (l1inv) asm volatile("buffer_inv" ::: "memory");  // CU L1 only
  }
  __syncthreads();
}

__global__ void rnn_init(unsigned char* ws) {
  const uint4 z = {0u, 0u, 0u, 0u};
  uint4* p = (uint4*)ws;
  size_t n = ZERO_BYTES / 16;
  for (size_t j = (size_t)blockIdx.x * blockDim.x + threadIdx.x; j < n;
       j += (size_t)gridDim.x * blockDim.x)
    p[j] = z;
}

// embW[v][u] = sum_e emb[v][e] * Wx0[e][u], stored bf16. grid (V/64, U/64), 256 thr.
__global__ __launch_bounds__(256) void embw_gemm(const float* __restrict__ emb,
                                                 const float* __restrict__ Wx0,
                                                 unsigned short* __restrict__ embW) {
  const int tid = threadIdx.x;
  const int lane = tid & 63;
  const int wv = tid >> 6;  // 4 waves = 4 row sub-tiles
  const int arow = lane & 15;
  const int kgrp = (lane >> 4) * 8;
  const int vrow = blockIdx.x * 64 + wv * 16;

  bf16x8 a[4];
  for (int kt = 0; kt < 4; ++kt) {
    const float* p = emb + (size_t)(vrow + arow) * E_ + kt * 32 + kgrp;
    float4 f0 = ((const float4*)p)[0];
    float4 f1 = ((const float4*)p)[1];
    us8 u;
    u[0] = f2b(f0.x); u[1] = f2b(f0.y); u[2] = f2b(f0.z); u[3] = f2b(f0.w);
    u[4] = f2b(f1.x); u[5] = f2b(f1.y); u[6] = f2b(f1.z); u[7] = f2b(f1.w);
    a[kt] = __builtin_bit_cast(bf16x8, u);
  }
  const int c0 = blockIdx.y * 64;
  for (int nt = 0; nt < 4; ++nt) {
    const int col = c0 + nt * 16 + (lane & 15);
    f32x4 acc = {0.f, 0.f, 0.f, 0.f};
    for (int kt = 0; kt < 4; ++kt) {
      us8 ub;
      for (int j = 0; j < 8; ++j)
        ub[j] = f2b(Wx0[(size_t)(kt * 32 + kgrp + j) * U_ + col]);
      acc = __builtin_amdgcn_mfma_f32_16x16x32_bf16(a[kt], __builtin_bit_cast(bf16x8, ub),
                                                    acc, 0, 0, 0);
    }
    const int crow = vrow + (lane >> 4) * 4;
    for (int i = 0; i < 4; ++i)
      embW[(size_t)(crow + i) * U_ + col] = f2b(acc[i]);
  }
}

template <bool FAST>
__device__ __forceinline__ void rnn_loop(
    const int* __restrict__ tokens, const unsigned short* __restrict__ embW,
    unsigned short* h0h, unsigned short* h0l, unsigned short* h1h,
    unsigned short* h1l, uint32* ctr, const unsigned short* sWh0h,
    const unsigned short* sWh0l, const unsigned short* sWx1h,
    const unsigned short* sWh1h, const unsigned short* sWh1l, int g, int tid,
    int r0, int c0, int colL, int rowB, int kgrp, int rowA, float b0v, float b1v) {
  // Prefetch window-0 tokens + embW acc-init (per-lane, no LDS staging).
  unsigned short embPre[4];
  for (int i = 0; i < 4; ++i) {
    int tk = tokens[(size_t)(r0 + rowB + i) * T_ + 0];
    embPre[i] = embW[(size_t)tk * U_ + c0 + colL];
  }

  // Window W(t): compute h1'(t-1) (lagged) and h0'(t); ONE barrier per window.
  for (int t = 0; t <= T_; ++t) {
    const size_t rb0 = (size_t)((t & 1) ^ 1) * (B_ * U_);  // h0'(t-1)

    // ---- load h0'(t-1) fragments ONCE (reused by layer-1 Wx1 and layer-0 Wh0)
    bf16x8 h0h_r[16], h0l_r[16];
    {
      const unsigned short* aph = h0h + rb0 + (size_t)rowA * U_ + kgrp;
      const unsigned short* apl = h0l + rb0 + (size_t)rowA * U_ + kgrp;
#pragma unroll
      for (int kt = 0; kt < 16; ++kt) {
        h0h_r[kt] = g_frag(aph + kt * 32);
        h0l_r[kt] = g_frag(apl + kt * 32);
      }
    }

    // ---- h1'(t-1) = tanh(h0'(t-1)@Wx1 + h1'(t-2)@Wh1 + b1) ----
    if (t >= 1) {
      const size_t rb1 = (size_t)(t & 1) * (B_ * U_);        // h1'(t-2)
      const size_t wb1 = (size_t)((t - 1) & 1) * (B_ * U_);  // h1'(t-1)
      f32x4 acc = {b1v, b1v, b1v, b1v};
      const unsigned short* a1h = h1h + rb1 + (size_t)rowA * U_ + kgrp;
      const unsigned short* a1l = h1l + rb1 + (size_t)rowA * U_ + kgrp;
#pragma unroll
      for (int kt = 0; kt < 16; ++kt) {
        bf16x8 ah = g_frag(a1h + kt * 32);
        bf16x8 al = g_frag(a1l + kt * 32);
        bf16x8 bxh = lds_frag(sWx1h, colL, kt * 32 + kgrp, U_);
        bf16x8 bh = lds_frag(sWh1h, colL, kt * 32 + kgrp, U_);
        acc = __builtin_amdgcn_mfma_f32_16x16x32_bf16(h0h_r[kt], bxh, acc, 0, 0, 0);
        acc = __builtin_amdgcn_mfma_f32_16x16x32_bf16(h0l_r[kt], bxh, acc, 0, 0, 0);
        acc = __builtin_amdgcn_mfma_f32_16x16x32_bf16(ah, bh, acc, 0, 0, 0);
        acc = __builtin_amdgcn_mfma_f32_16x16x32_bf16(al, bh, acc, 0, 0, 0);
        if (kt < 15) {
          bf16x8 bl = lds_frag(sWh1l, colL, kt * 32 + kgrp, 480);
          acc = __builtin_amdgcn_mfma_f32_16x16x32_bf16(ah, bl, acc, 0, 0, 0);
        }
      }
      size_t ob = wb1 + (size_t)(r0 + rowB) * U_ + (c0 + colL);
      for (int i = 0; i < 4; ++i) {
        float v = tanhf(acc[i]);
        unsigned short hi = f2b(v);
        st_h<FAST>(&h1h[ob + (size_t)i * U_], hi);
        st_h<FAST>(&h1l[ob + (size_t)i * U_], f2b(v - b2f(hi)));
      }
    }

    // ---- h0'(t) = tanh(embW[tok(t)] + h0'(t-1)@Wh0 + b0) ----
    if (t < T_) {
      const size_t wbuf = (size_t)(t & 1) * (B_ * U_);
      f32x4 acc;
      for (int i = 0; i < 4; ++i) acc[i] = b0v + b2f(embPre[i]);
#pragma unroll
      for (int kt = 0; kt < 16; ++kt) {
        bf16x8 bh = lds_frag(sWh0h, colL, kt * 32 + kgrp, U_);
        bf16x8 bl = lds_frag(sWh0l, colL, kt * 32 + kgrp, U_);
        acc = __builtin_amdgcn_mfma_f32_16x16x32_bf16(h0h_r[kt], bh, acc, 0, 0, 0);
        acc = __builtin_amdgcn_mfma_f32_16x16x32_bf16(h0l_r[kt], bh, acc, 0, 0, 0);
        acc = __builtin_amdgcn_mfma_f32_16x16x32_bf16(h0h_r[kt], bl, acc, 0, 0, 0);
      }
      size_t ob = wbuf + (size_t)(r0 + rowB) * U_ + (c0 + colL);
      for (int i = 0; i < 4; ++i) {
        float v = tanhf(acc[i]);
        unsigned short hi = f2b(v);
        st_h<FAST>(&h0h[ob + (size_t)i * U_], hi);
        st_h<FAST>(&h0l[ob + (size_t)i * U_], f2b(v - b2f(hi)));
      }

      // ---- prefetch NEXT window's tokens+embW init (values land in regs
      // before the barrier's vmcnt drain / invalidate).
      if (t + 1 < T_) {
        for (int i = 0; i < 4; ++i) {
          int tk = tokens[(size_t)(r0 + rowB + i) * T_ + (t + 1)];
          embPre[i] = embW[(size_t)tk * U_ + c0 + colL];
        }
      }
      bar_core(ctr, t, g, tid, /*fence=*/!FAST, /*l1inv=*/FAST);
    }
  }
}

__global__ __launch_bounds__(512, 2) void rnn_main(
    const int* __restrict__ tokens, const float* __restrict__ b0,
    const float* __restrict__ Wh0, const float* __restrict__ Wx1,
    const float* __restrict__ Wh1, const float* __restrict__ b1,
    unsigned char* ws) {
  __shared__ unsigned short sWh0h[NB * U_];   // 32 KB
  __shared__ unsigned short sWh0l[NB * U_];   // 32 KB
  __shared__ unsigned short sWx1h[NB * U_];   // 32 KB
  __shared__ unsigned short sWh1h[NB * U_];   // 32 KB
  __shared__ unsigned short sWh1l[NB * 480];  // 30 KB (K-tiles 0..14)
  __shared__ uint32 sFast;

  const int tid = threadIdx.x;
  const int bid = blockIdx.x;
  const int g = bid & (NG - 1);  // row group (mates share bid%8 -> same XCD if RR)
  const int c = bid >> 4;        // col chunk
  const int r0 = g * MB;
  const int c0 = c * NB;

  uint32* ctr = (uint32*)(ws + CTR_OFF);
  unsigned short* h0h = (unsigned short*)(ws + H0H_OFF);
  unsigned short* h0l = (unsigned short*)(ws + H0L_OFF);
  unsigned short* h1h = (unsigned short*)(ws + H1H_OFF);
  unsigned short* h1l = (unsigned short*)(ws + H1L_OFF);
  const unsigned short* embW = (const unsigned short*)(ws + EMBW_OFF);

  // ---- stage weight slices: f32 global -> bf16 hi(+lo) swizzled LDS ----
  for (int idx = tid; idx < NB * U_; idx += 512) {
    int cl = idx & 31, k = idx >> 5;
    float v = Wh0[(size_t)k * U_ + c0 + cl];
    unsigned short hi = f2b(v);
    uint32 off = (uint32)((cl * U_ + k) * 2) ^ (uint32)((cl & 7) << 4);
    *(unsigned short*)((char*)sWh0h + off) = hi;
    *(unsigned short*)((char*)sWh0l + off) = f2b(v - b2f(hi));
  }
  for (int idx = tid; idx < NB * U_; idx += 512) {
    int cl = idx & 31, k = idx >> 5;
    float v = Wx1[(size_t)k * U_ + c0 + cl];
    uint32 off = (uint32)((cl * U_ + k) * 2) ^ (uint32)((cl & 7) << 4);
    *(unsigned short*)((char*)sWx1h + off) = f2b(v);
  }
  for (int idx = tid; idx < NB * U_; idx += 512) {
    int cl = idx & 31, k = idx >> 5;
    float v = Wh1[(size_t)k * U_ + c0 + cl];
    unsigned short hi = f2b(v);
    uint32 off = (uint32)((cl * U_ + k) * 2) ^ (uint32)((cl & 7) << 4);
    *(unsigned short*)((char*)sWh1h + off) = hi;
    if (k < 480) {
      uint32 offl = (uint32)((cl * 480 + k) * 2) ^ (uint32)((cl & 7) << 4);
      *(unsigned short*)((char*)sWh1l + offl) = f2b(v - b2f(hi));
    }
  }

  // ---- runtime XCD co-residency check (G16: never ASSUME the mapping) ----
  {
    uint32 xcd;
    asm volatile("s_getreg_b32 %0, hwreg(HW_REG_XCC_ID)" : "=s"(xcd));
    uint32* xm = (uint32*)(ws + XMASK_OFF) + (uint32)g * 16;
    if (tid == 0)
      __hip_atomic_fetch_or(xm, 1u << (xcd & 31u), __ATOMIC_RELAXED,
                            __HIP_MEMORY_SCOPE_AGENT);
    bar_core(ctr, T_, g, tid, /*fence=*/true, /*l1inv=*/false);
    if (tid == 0) {
      uint32 m = __hip_atomic_load(xm, __ATOMIC_RELAXED, __HIP_MEMORY_SCOPE_AGENT);
      sFast = (__popc(m) == 1) ? 1u : 0u;
    }
  }

  const int lane = tid & 63;
  const int wv = tid >> 6;        // 8 waves
  const int mt = wv >> 1;         // 0..3  M tile
  const int nt = wv & 1;          // 0..1  N tile
  const int colL = nt * 16 + (lane & 15);
  const int rowB = mt * 16 + ((lane >> 4) << 2);
  const int kgrp = (lane >> 4) * 8;
  const int rowA = r0 + mt * 16 + (lane & 15);
  const float b0v = b0[c0 + colL];
  const float b1v = b1[c0 + colL];

  __syncthreads();
  const bool fast = (sFast != 0);

  if (fast)
    rnn_loop<true>(tokens, embW, h0h, h0l, h1h, h1l, ctr, sWh0h, sWh0l, sWx1h,
                   sWh1h, sWh1l, g, tid, r0, c0, colL, rowB, kgrp, rowA, b0v, b1v);
  else
    rnn_loop<false>(tokens, embW, h0h, h0l, h1h, h1l, ctr, sWh0h, sWh0l, sWx1h,
                    sWh1h, sWh1l, g, tid, r0, c0, colL, rowB, kgrp, rowA, b0v, b1v);
}

__global__ void rnn_final(const unsigned short* __restrict__ h1h,
                          const unsigned short* __restrict__ h1l,
                          const float* __restrict__ Wo,
                          const float* __restrict__ bo, float* __restrict__ out) {
  int lane = threadIdx.x & 63;
  int b = blockIdx.x * 4 + (threadIdx.x >> 6);
  us8 hh = *(const us8*)(h1h + (size_t)b * U_ + lane * 8);
  us8 hl = *(const us8*)(h1l + (size_t)b * U_ + lane * 8);
  const float4* wp = (const float4*)(Wo + lane * 8);
  float4 w0 = wp[0], w1 = wp[1];
  float s = (b2f(hh[0]) + b2f(hl[0])) * w0.x + (b2f(hh[1]) + b2f(hl[1])) * w0.y +
            (b2f(hh[2]) + b2f(hl[2])) * w0.z + (b2f(hh[3]) + b2f(hl[3])) * w0.w +
            (b2f(hh[4]) + b2f(hl[4])) * w1.x + (b2f(hh[5]) + b2f(hl[5])) * w1.y +
            (b2f(hh[6]) + b2f(hl[6])) * w1.z + (b2f(hh[7]) + b2f(hl[7])) * w1.w;
  for (int off = 32; off > 0; off >>= 1) s += __shfl_down(s, off, 64);
  if (lane == 0) out[b] = 1.0f / (1.0f + expf(-(s + bo[0])));
}

extern "C" void kernel_launch(void* const* d_in, const int* in_sizes, int n_in,
                              void* d_out, int out_size, void* d_ws, size_t ws_size,
                              hipStream_t stream) {
  const int* tokens = (const int*)d_in[0];
  const float* emb = (const float*)d_in[1];
  const float* Wx0 = (const float*)d_in[2];
  const float* Wh0 = (const float*)d_in[3];
  const float* b0 = (const float*)d_in[4];
  const float* Wx1 = (const float*)d_in[5];
  const float* Wh1 = (const float*)d_in[6];
  const float* b1 = (const float*)d_in[7];
  const float* Wo = (const float*)d_in[8];
  const float* bo = (const float*)d_in[9];
  unsigned char* ws = (unsigned char*)d_ws;
  float* out = (float*)d_out;

  hipLaunchKernelGGL(rnn_init, dim3(1024), dim3(256), 0, stream, ws);
  hipLaunchKernelGGL(embw_gemm, dim3(V_ / 64, U_ / 64), dim3(256), 0, stream,
                     emb, Wx0, (unsigned short*)(ws + EMBW_OFF));
  hipLaunchKernelGGL(rnn_main, dim3(NC * NG), dim3(512), 0, stream, tokens,
                     b0, Wh0, Wx1, Wh1, b1, ws);
  // final h1'(127) lives in buffer 127&1 == 1
  hipLaunchKernelGGL(rnn_final, dim3(256), dim3(256), 0, stream,
                     (const unsigned short*)(ws + H1H_OFF) + (size_t)1 * B_ * U_,
                     (const unsigned short*)(ws + H1L_OFF) + (size_t)1 * B_ * U_,
                     Wo, bo, out);
}